// Round 19
// baseline (102.669 us; speedup 1.0000x reference)
//
#include <hip/hip_runtime.h>

#define SN 2048
#define SDIM 1024
#define SNH 16
#define SDK 64
#define NZ 4

typedef short short8 __attribute__((ext_vector_type(8)));
typedef unsigned short u16;
typedef u16 u16x4 __attribute__((ext_vector_type(4)));
typedef u16 u16x8 __attribute__((ext_vector_type(8)));
typedef unsigned u32x4 __attribute__((ext_vector_type(4)));
typedef float f32x4 __attribute__((ext_vector_type(4)));

// round-to-nearest-even fp32 -> bf16
__device__ __forceinline__ u16 f2b(float f){
  unsigned u = __builtin_bit_cast(unsigned, f);
  u += 0x7fffu + ((u >> 16) & 1u);
  return (u16)(u >> 16);
}

__device__ __forceinline__ float b2f(u16 b){
  unsigned u = ((unsigned)b) << 16;
  return __builtin_bit_cast(float, u);
}

__device__ __forceinline__ float fast_exp2(float x){
#if __has_builtin(__builtin_amdgcn_exp2f)
  return __builtin_amdgcn_exp2f(x);
#else
  float r; asm("v_exp_f32 %0, %1" : "=v"(r) : "v"(x)); return r;
#endif
}

// pack two f32 into (bf16(lo), bf16(hi)) by truncation - single v_perm_b32
__device__ __forceinline__ unsigned packbf(float lo, float hi){
  unsigned a = __builtin_bit_cast(unsigned, lo);
  unsigned b = __builtin_bit_cast(unsigned, hi);
#if __has_builtin(__builtin_amdgcn_perm)
  return __builtin_amdgcn_perm(b, a, 0x07060302u);  // bytes: [a2,a3,b2,b3]
#else
  return (a >> 16) | (b & 0xffff0000u);
#endif
}

__device__ __forceinline__ void async_cp16(const void* g, void* l){
  __builtin_amdgcn_global_load_lds(
      (const __attribute__((address_space(1))) unsigned*)g,
      (__attribute__((address_space(3))) unsigned*)l, 16, 0, 0);
}

// ---------------- fused fp32 -> bf16 conversion (x, Wq, Wk, Wv) ----------------
__global__ void conv_all(const float* __restrict__ x, const float* __restrict__ wq,
                         const float* __restrict__ wk, const float* __restrict__ wv,
                         u16* __restrict__ xb, u16* __restrict__ wb){
  const int NX4 = (SN * SDIM) / 4;
  const int NW4 = (SDIM * SDIM) / 4;   // 1<<18
  const int total = NX4 + 3 * NW4;
  int i = blockIdx.x * blockDim.x + threadIdx.x;
  int stride = gridDim.x * blockDim.x;
  for (int idx = i; idx < total; idx += stride){
    const float* src; u16* dst; int off;
    if (idx < NX4){ src = x; dst = xb; off = idx; }
    else {
      int t = idx - NX4; int ws = t >> 18; off = t & (NW4 - 1);
      src = (ws == 0) ? wq : ((ws == 1) ? wk : wv);
      dst = wb + (size_t)ws * SDIM * SDIM;
    }
    float4 v = reinterpret_cast<const float4*>(src)[off];
    u16x4 o = { f2b(v.x), f2b(v.y), f2b(v.z), f2b(v.w) };
    *reinterpret_cast<u16x4*>(&dst[(size_t)off * 4]) = o;
  }
}

// ---------------- projection GEMM: out = x @ W^T (bf16 in, bf16 out) ----------------
// 64x128 tiles, 512 threads (8 waves = 2m x 2n space x 2 K-halves), grid
// (32, 8, 3) = 768 blocks (3/CU, 24 waves/CU). Wave-tile 32x64 (acc[2][4]).
// K-half partials reduced through a 32 KB LDS scratch (overlays Bsm).
// XCD-chunked bijective swizzle (tm-fastest). z==0 -> q (scaled 0.125*log2e),
// z==1 -> k, z==2 -> v stored TRANSPOSED.
__global__ __launch_bounds__(512, 6) void proj_gemm(const u16* __restrict__ xb, const u16* __restrict__ wb,
                                                    u16* __restrict__ qb, u16* __restrict__ kb,
                                                    u16* __restrict__ vtb){
  __shared__ __align__(16) u16 Asm[2][64 * 64];    // 16 KB
  __shared__ __align__(16) u16 Bsm[2][128 * 64];   // 32 KB
  const int tid = threadIdx.x, w = tid >> 6, lane = tid & 63;
  const int r = lane & 15, hi = lane >> 4;

  int flat = blockIdx.x + 32 * blockIdx.y + 256 * blockIdx.z;  // [0,768)
  int sw = (flat & 7) * 96 + (flat >> 3);                      // bijective
  const int tm = (sw & 31) * 64;
  const int tn = ((sw >> 5) & 7) * 128;
  const int z = sw >> 8;

  const u16* W = wb + (size_t)z * SDIM * SDIM;
  const int kk = w >> 2;                       // K-half owned by this wave
  const int wr = (w >> 1) & 1, wc = w & 1;     // 2 x 2 wave grid, 32x64 per wave
  const int srow = lane >> 3;
  const int schunk = (lane & 7) ^ (lane >> 3); // pre-swizzled source chunk
  f32x4 acc[2][4] = {};

  auto stage = [&](int b, int kt){
    async_cp16(xb + (size_t)(tm + w * 8 + srow) * SDIM + kt + schunk * 8, &Asm[b][w * 8 * 64]);
#pragma unroll
    for (int c = 0; c < 2; c++){
      int row = w * 16 + c * 8;
      async_cp16(W + (size_t)(tn + row + srow) * SDIM + kt + schunk * 8, &Bsm[b][row * 64]);
    }
  };

  stage(0, 0);
  asm volatile("s_waitcnt vmcnt(0)" ::: "memory");
  __builtin_amdgcn_s_barrier();
  __builtin_amdgcn_sched_barrier(0);

  int cur = 0;
  for (int kt = 0; kt < SDIM; kt += 64){
    if (kt + 64 < SDIM) stage(cur ^ 1, kt + 64);
    __builtin_amdgcn_s_setprio(1);
    {
      short8 af[2], bf[4];
      int cc = (kk * 4 + hi) ^ (r & 7);
#pragma unroll
      for (int mr = 0; mr < 2; mr++)
        af[mr] = *reinterpret_cast<const short8*>(&Asm[cur][(wr * 32 + mr * 16 + r) * 64 + cc * 8]);
#pragma unroll
      for (int nr = 0; nr < 4; nr++)
        bf[nr] = *reinterpret_cast<const short8*>(&Bsm[cur][(wc * 64 + nr * 16 + r) * 64 + cc * 8]);
#pragma unroll
      for (int mr = 0; mr < 2; mr++)
#pragma unroll
        for (int nr = 0; nr < 4; nr++)
          acc[mr][nr] = __builtin_amdgcn_mfma_f32_16x16x32_bf16(af[mr], bf[nr], acc[mr][nr], 0, 0, 0);
    }
    __builtin_amdgcn_s_setprio(0);
    asm volatile("s_waitcnt vmcnt(0)" ::: "memory");
    __builtin_amdgcn_s_barrier();
    __builtin_amdgcn_sched_barrier(0);
    cur ^= 1;
  }

  // ---- cross-K-half reduction through LDS scratch (overlays Bsm: 32 KB) ----
  float* scr = reinterpret_cast<float*>(&Bsm[0][0]);
  const int slot = w & 3;
  if (kk == 1){
#pragma unroll
    for (int mr = 0; mr < 2; mr++)
#pragma unroll
      for (int nr = 0; nr < 4; nr++){
        int fid = mr * 4 + nr;
        int a = slot * 2048 + fid * 256 + r * 16 + ((hi + r) & 3) * 4;
        *reinterpret_cast<f32x4*>(&scr[a]) = acc[mr][nr];
      }
  }
  __syncthreads();
  if (kk == 0){
#pragma unroll
    for (int mr = 0; mr < 2; mr++)
#pragma unroll
      for (int nr = 0; nr < 4; nr++){
        int fid = mr * 4 + nr;
        int a = slot * 2048 + fid * 256 + r * 16 + ((hi + r) & 3) * 4;
        f32x4 t = *reinterpret_cast<const f32x4*>(&scr[a]);
        acc[mr][nr][0] += t[0]; acc[mr][nr][1] += t[1];
        acc[mr][nr][2] += t[2]; acc[mr][nr][3] += t[3];
      }

    if (z == 2){
#pragma unroll
      for (int mr = 0; mr < 2; mr++)
#pragma unroll
        for (int nr = 0; nr < 4; nr++){
          u16x4 o4 = { f2b(acc[mr][nr][0]), f2b(acc[mr][nr][1]),
                       f2b(acc[mr][nr][2]), f2b(acc[mr][nr][3]) };
          int col = tn + wc * 64 + nr * 16 + r;          // d index
          int row = tm + wr * 32 + mr * 16 + hi * 4;     // n index base
          *reinterpret_cast<u16x4*>(&vtb[(size_t)col * SN + row]) = o4;
        }
    } else {
      u16* outp = (z == 0) ? qb : kb;
      const float scl = (z == 0) ? 0.18033688011112043f : 1.0f;  // 0.125*log2(e)
#pragma unroll
      for (int mr = 0; mr < 2; mr++)
#pragma unroll
        for (int nr = 0; nr < 4; nr++)
#pragma unroll
          for (int j = 0; j < 4; j++){
            int row = tm + wr * 32 + mr * 16 + hi * 4 + j;
            int col = tn + wc * 64 + nr * 16 + r;
            outp[(size_t)row * SDIM + col] = f2b(acc[mr][nr][j] * scl);
          }
    }
  }
}

// ---------------- flash attention, ZERO-LDS / ZERO-BARRIER, KV-split x4 ----------------
// Per-XCD K/V working set is 1 MB (L2-resident via swizzle), so K/V fragments
// are read DIRECTLY from global (L2) — no staging, no barriers, no vmcnt(0)
// drains. Each wave free-runs its 8 KV tiles; exp VALU of one wave overlaps
// MFMA of others with no sync amplification. Same kv-permutation folded into
// the global address -> values and summation order bit-identical to r13.
// grid: (SN/128, SNH, 4) = 1024 blocks (4/CU), 256 threads (4 indep waves).
__global__ __launch_bounds__(256) void attn(const u16* __restrict__ qb, const u16* __restrict__ kb,
                                            const u16* __restrict__ vtb,
                                            u16* __restrict__ po, float* __restrict__ pl){
  const int tid = threadIdx.x, w = tid >> 6, lane = tid & 63;
  const int r = lane & 15, hi = lane >> 4;

  // bijective XCD swizzle over 1024 blocks: XCD i gets one z-quarter, 8 heads
  int flat = blockIdx.x + 16 * blockIdx.y + 256 * blockIdx.z;
  int sw = (flat & 7) * 128 + (flat >> 3);
  const int q0 = (sw & 15) * 128, h = (sw >> 4) & 15, z = sw >> 8;

  // Q B-fragments, 2 subtiles (q = q0 + w*32 + sub*16 + r; 0.125*log2e folded)
  short8 aq[2][2];
#pragma unroll
  for (int sub = 0; sub < 2; sub++){
    int qrow = q0 + w * 32 + sub * 16 + r;
    aq[sub][0] = *reinterpret_cast<const short8*>(&qb[(size_t)qrow * SDIM + h * SDK + hi * 8]);
    aq[sub][1] = *reinterpret_cast<const short8*>(&qb[(size_t)qrow * SDIM + h * SDK + 32 + hi * 8]);
  }
  f32x4 oacc[2][4] = {};
  float lacc0 = 0.f, lacc1 = 0.f;   // per-lane partial row-sums (q = r per subtile)

  // per-lane kv offset within a 64-tile for A-frag row (ct*16 + r):
  // kvp = 32*(ct>>1) + 8*(r>>2) + 4*(ct&1) + (r&3)
  const int kvbase = 8 * (r >> 2) + (r & 3);

  const int t0 = z * (SN / 4);
  const int NT = (SN / 4) / 64;   // 8 tiles

  for (int it = 0; it < NT; ++it){
    const int t = t0 + it * 64;

    // K A-fragments straight from global (L2-hot)
    short8 bk[4][2];
#pragma unroll
    for (int ct = 0; ct < 4; ct++){
      int kv = t + 32 * (ct >> 1) + 4 * (ct & 1) + kvbase;
      const u16* kp = kb + (size_t)kv * SDIM + h * SDK + hi * 8;
      bk[ct][0] = *reinterpret_cast<const short8*>(kp);
      bk[ct][1] = *reinterpret_cast<const short8*>(kp + 32);
    }

    // S^T = K Q^T (swapped): lane (r,hi), slot (ct,j) holds physical
    // kv = t + 32*(ct>>1) + 8*hi + 4*(ct&1) + j
    f32x4 s0[4], s1[4];
    __builtin_amdgcn_s_setprio(1);
#pragma unroll
    for (int ct = 0; ct < 4; ct++){
      f32x4 zero = {};
      s0[ct] = __builtin_amdgcn_mfma_f32_16x16x32_bf16(bk[ct][0], aq[0][0], zero, 0, 0, 0);
      s1[ct] = __builtin_amdgcn_mfma_f32_16x16x32_bf16(bk[ct][0], aq[1][0], zero, 0, 0, 0);
      s0[ct] = __builtin_amdgcn_mfma_f32_16x16x32_bf16(bk[ct][1], aq[0][1], s0[ct], 0, 0, 0);
      s1[ct] = __builtin_amdgcn_mfma_f32_16x16x32_bf16(bk[ct][1], aq[1][1], s1[ct], 0, 0, 0);
    }
    __builtin_amdgcn_s_setprio(0);

    // V B-fragments from global — issued here so they fly under EXPPACK
    short8 bv[4][2];
#pragma unroll
    for (int dt = 0; dt < 4; dt++){
      const u16* vp = vtb + (size_t)(h * SDK + dt * 16 + r) * SN + t + hi * 8;
      bv[dt][0] = *reinterpret_cast<const short8*>(vp);
      bv[dt][1] = *reinterpret_cast<const short8*>(vp + 32);
    }

    // p = 2^s (bounded scores in log2 domain); pack into 16x16x32 A-fragments
    short8 paf0[2], paf1[2];
    {
      uint2 pc0[4], pc1[4];
#pragma unroll
      for (int ct = 0; ct < 4; ct++){
        float a0 = fast_exp2(s0[ct][0]), a1 = fast_exp2(s0[ct][1]);
        float a2 = fast_exp2(s0[ct][2]), a3 = fast_exp2(s0[ct][3]);
        lacc0 += (a0 + a1) + (a2 + a3);
        pc0[ct].x = packbf(a0, a1);
        pc0[ct].y = packbf(a2, a3);
        float b0 = fast_exp2(s1[ct][0]), b1 = fast_exp2(s1[ct][1]);
        float b2 = fast_exp2(s1[ct][2]), b3 = fast_exp2(s1[ct][3]);
        lacc1 += (b0 + b1) + (b2 + b3);
        pc1[ct].x = packbf(b0, b1);
        pc1[ct].y = packbf(b2, b3);
      }
#pragma unroll
      for (int c = 0; c < 2; c++){
        u32x4 u0 = { pc0[2*c].x, pc0[2*c].y, pc0[2*c+1].x, pc0[2*c+1].y };
        u32x4 u1 = { pc1[2*c].x, pc1[2*c].y, pc1[2*c+1].x, pc1[2*c+1].y };
        paf0[c] = __builtin_bit_cast(short8, u0);
        paf1[c] = __builtin_bit_cast(short8, u1);
      }
    }

    // O += P V
    __builtin_amdgcn_s_setprio(1);
#pragma unroll
    for (int dt = 0; dt < 4; dt++){
#pragma unroll
      for (int c = 0; c < 2; c++){
        oacc[0][dt] = __builtin_amdgcn_mfma_f32_16x16x32_bf16(paf0[c], bv[dt][c], oacc[0][dt], 0, 0, 0);
        oacc[1][dt] = __builtin_amdgcn_mfma_f32_16x16x32_bf16(paf1[c], bv[dt][c], oacc[1][dt], 0, 0, 0);
      }
    }
    __builtin_amdgcn_s_setprio(0);
  }

  // reduce l across the 4 hi-groups (q = r per subtile)
  lacc0 += __shfl_xor(lacc0, 16); lacc0 += __shfl_xor(lacc0, 32);
  lacc1 += __shfl_xor(lacc1, 16); lacc1 += __shfl_xor(lacc1, 32);

  const size_t zh = (size_t)z * SNH + h;
#pragma unroll
  for (int sub = 0; sub < 2; sub++)
#pragma unroll
    for (int dt = 0; dt < 4; dt++)
#pragma unroll
      for (int j = 0; j < 4; j++){
        int row = q0 + w * 32 + sub * 16 + hi * 4 + j;
        po[(zh * SN + row) * SDK + dt * 16 + r] = f2b(oacc[sub][dt][j]);
      }
  if (hi == 0){
    pl[zh * SN + q0 + w * 32 + r] = lacc0;
    pl[zh * SN + q0 + w * 32 + 16 + r] = lacc1;
  }
}

// ---------------- merge the four KV quarters (shared implicit max of 0) ----------------
// one thread per 8 output elems: b128 po reads, 2x dwordx4 out writes
__global__ void merge(const u16* __restrict__ po, const float* __restrict__ pl,
                      float* __restrict__ out){
  int gid = blockIdx.x * blockDim.x + threadIdx.x;  // 262144 threads
  int c8 = gid & 7;
  int rowid = gid >> 3;          // q*16 + h
  int h = rowid & 15, q = rowid >> 4;
  float L = 0.f;
  float o[8] = {};
#pragma unroll
  for (int z = 0; z < NZ; z++){
    size_t zh = (size_t)z * SNH + h;
    L += pl[zh * SN + q];
    u16x8 a = *reinterpret_cast<const u16x8*>(&po[(zh * SN + q) * SDK + c8 * 8]);
#pragma unroll
    for (int e = 0; e < 8; e++) o[e] += b2f(a[e]);
  }
  float rL = 1.0f / L;
  float4 o0 = { o[0] * rL, o[1] * rL, o[2] * rL, o[3] * rL };
  float4 o1 = { o[4] * rL, o[5] * rL, o[6] * rL, o[7] * rL };
  float* dst = &out[(size_t)q * SDIM + h * SDK + c8 * 8];
  *reinterpret_cast<float4*>(dst) = o0;
  *reinterpret_cast<float4*>(dst + 4) = o1;
}

extern "C" void kernel_launch(void* const* d_in, const int* in_sizes, int n_in,
                              void* d_out, int out_size, void* d_ws, size_t ws_size,
                              hipStream_t stream){
  const float* x  = (const float*)d_in[0];
  const float* Wq = (const float*)d_in[2];
  const float* Wk = (const float*)d_in[3];
  const float* Wv = (const float*)d_in[4];
  float* out = (float*)d_out;

  char* ws = (char*)d_ws;
  u16* xb  = (u16*)(ws);                   // 4 MB   x bf16
  u16* wb  = (u16*)(ws + (4  << 20));      // 6 MB   Wq|Wk|Wv bf16
  u16* qb  = (u16*)(ws + (10 << 20));      // 4 MB   q bf16 (pre-scaled by 0.125*log2e)
  u16* kb  = (u16*)(ws + (14 << 20));      // 4 MB   k bf16
  u16* vtb = (u16*)(ws + (18 << 20));      // 4 MB   v^T bf16 [1024][2048]
  u16* po  = (u16*)(ws + (22 << 20));      // 16 MB  [4][16][2048][64] bf16
  float* pl = (float*)(ws + (38 << 20));   // 512 KB [4][16][2048] f32

  conv_all<<<2048, 256, 0, stream>>>(x, Wq, Wk, Wv, xb, wb);

  dim3 pg(SN / 64, SDIM / 128, 3);         // (32, 8, 3) = 768 blocks, 64x128 tiles
  proj_gemm<<<pg, 512, 0, stream>>>(xb, wb, qb, kb, vtb);

  dim3 ag(SN / 128, SNH, NZ);              // (16, 16, 4) = 1024 blocks, 256 threads
  attn<<<ag, 256, 0, stream>>>(qb, kb, vtb, po, pl);

  merge<<<(SN * SNH * 8) / 256, 256, 0, stream>>>(po, pl, out);
}

// Round 20
// 55.931 us; speedup vs baseline: 1.8357x; 1.8357x over previous
//
#include <hip/hip_runtime.h>

#define SN 2048
#define SDIM 1024
#define SNH 16
#define SDK 64
#define NZ 4

typedef short short8 __attribute__((ext_vector_type(8)));
typedef short s16x4 __attribute__((ext_vector_type(4)));
typedef unsigned short u16;
typedef u16 u16x4 __attribute__((ext_vector_type(4)));
typedef u16 u16x8 __attribute__((ext_vector_type(8)));
typedef unsigned u32x4 __attribute__((ext_vector_type(4)));
typedef float f32x4 __attribute__((ext_vector_type(4)));

// round-to-nearest-even fp32 -> bf16
__device__ __forceinline__ u16 f2b(float f){
  unsigned u = __builtin_bit_cast(unsigned, f);
  u += 0x7fffu + ((u >> 16) & 1u);
  return (u16)(u >> 16);
}

__device__ __forceinline__ float b2f(u16 b){
  unsigned u = ((unsigned)b) << 16;
  return __builtin_bit_cast(float, u);
}

__device__ __forceinline__ float fast_exp2(float x){
#if __has_builtin(__builtin_amdgcn_exp2f)
  return __builtin_amdgcn_exp2f(x);
#else
  float r; asm("v_exp_f32 %0, %1" : "=v"(r) : "v"(x)); return r;
#endif
}

// pack two f32 into (bf16(lo), bf16(hi)) by truncation - single v_perm_b32
__device__ __forceinline__ unsigned packbf(float lo, float hi){
  unsigned a = __builtin_bit_cast(unsigned, lo);
  unsigned b = __builtin_bit_cast(unsigned, hi);
#if __has_builtin(__builtin_amdgcn_perm)
  return __builtin_amdgcn_perm(b, a, 0x07060302u);  // bytes: [a2,a3,b2,b3]
#else
  return (a >> 16) | (b & 0xffff0000u);
#endif
}

__device__ __forceinline__ void async_cp16(const void* g, void* l){
  __builtin_amdgcn_global_load_lds(
      (const __attribute__((address_space(1))) unsigned*)g,
      (__attribute__((address_space(3))) unsigned*)l, 16, 0, 0);
}

// ---------------- fused fp32 -> bf16 conversion (x, Wq, Wk, Wv) ----------------
__global__ void conv_all(const float* __restrict__ x, const float* __restrict__ wq,
                         const float* __restrict__ wk, const float* __restrict__ wv,
                         u16* __restrict__ xb, u16* __restrict__ wb){
  const int NX4 = (SN * SDIM) / 4;
  const int NW4 = (SDIM * SDIM) / 4;   // 1<<18
  const int total = NX4 + 3 * NW4;
  int i = blockIdx.x * blockDim.x + threadIdx.x;
  int stride = gridDim.x * blockDim.x;
  for (int idx = i; idx < total; idx += stride){
    const float* src; u16* dst; int off;
    if (idx < NX4){ src = x; dst = xb; off = idx; }
    else {
      int t = idx - NX4; int ws = t >> 18; off = t & (NW4 - 1);
      src = (ws == 0) ? wq : ((ws == 1) ? wk : wv);
      dst = wb + (size_t)ws * SDIM * SDIM;
    }
    float4 v = reinterpret_cast<const float4*>(src)[off];
    u16x4 o = { f2b(v.x), f2b(v.y), f2b(v.z), f2b(v.w) };
    *reinterpret_cast<u16x4*>(&dst[(size_t)off * 4]) = o;
  }
}

// ---------------- projection GEMM: out = x @ W^T (bf16 in, bf16 out) ----------------
// 64x128 tiles, 512 threads (8 waves = 2m x 2n space x 2 K-halves), grid
// (32, 8, 3) = 768 blocks (3/CU, 24 waves/CU). Wave-tile 32x64 (acc[2][4]).
// K-half partials reduced through a 32 KB LDS scratch (overlays Bsm).
// z==0 -> q (scaled 0.125*log2e), z==1 -> k, z==2 -> v stored TRANSPOSED.
__global__ __launch_bounds__(512, 6) void proj_gemm(const u16* __restrict__ xb, const u16* __restrict__ wb,
                                                    u16* __restrict__ qb, u16* __restrict__ kb,
                                                    u16* __restrict__ vtb){
  __shared__ __align__(16) u16 Asm[2][64 * 64];    // 16 KB
  __shared__ __align__(16) u16 Bsm[2][128 * 64];   // 32 KB
  const int tid = threadIdx.x, w = tid >> 6, lane = tid & 63;
  const int r = lane & 15, hi = lane >> 4;
  const int tm = blockIdx.x * 64, tn = blockIdx.y * 128;
  const int z = blockIdx.z;
  const u16* W = wb + (size_t)z * SDIM * SDIM;
  const int kk = w >> 2;                       // K-half owned by this wave
  const int wr = (w >> 1) & 1, wc = w & 1;     // 2 x 2 wave grid, 32x64 per wave
  const int srow = lane >> 3;
  const int schunk = (lane & 7) ^ (lane >> 3); // pre-swizzled source chunk
  f32x4 acc[2][4] = {};

  auto stage = [&](int b, int kt){
    async_cp16(xb + (size_t)(tm + w * 8 + srow) * SDIM + kt + schunk * 8, &Asm[b][w * 8 * 64]);
#pragma unroll
    for (int c = 0; c < 2; c++){
      int row = w * 16 + c * 8;
      async_cp16(W + (size_t)(tn + row + srow) * SDIM + kt + schunk * 8, &Bsm[b][row * 64]);
    }
  };

  stage(0, 0);
  asm volatile("s_waitcnt vmcnt(0)" ::: "memory");
  __builtin_amdgcn_s_barrier();
  __builtin_amdgcn_sched_barrier(0);

  int cur = 0;
  for (int kt = 0; kt < SDIM; kt += 64){
    if (kt + 64 < SDIM) stage(cur ^ 1, kt + 64);
    __builtin_amdgcn_s_setprio(1);
    {
      short8 af[2], bf[4];
      int cc = (kk * 4 + hi) ^ (r & 7);
#pragma unroll
      for (int mr = 0; mr < 2; mr++)
        af[mr] = *reinterpret_cast<const short8*>(&Asm[cur][(wr * 32 + mr * 16 + r) * 64 + cc * 8]);
#pragma unroll
      for (int nr = 0; nr < 4; nr++)
        bf[nr] = *reinterpret_cast<const short8*>(&Bsm[cur][(wc * 64 + nr * 16 + r) * 64 + cc * 8]);
#pragma unroll
      for (int mr = 0; mr < 2; mr++)
#pragma unroll
        for (int nr = 0; nr < 4; nr++)
          acc[mr][nr] = __builtin_amdgcn_mfma_f32_16x16x32_bf16(af[mr], bf[nr], acc[mr][nr], 0, 0, 0);
    }
    __builtin_amdgcn_s_setprio(0);
    asm volatile("s_waitcnt vmcnt(0)" ::: "memory");
    __builtin_amdgcn_s_barrier();
    __builtin_amdgcn_sched_barrier(0);
    cur ^= 1;
  }

  // ---- cross-K-half reduction through LDS scratch (overlays Bsm: 32 KB) ----
  float* scr = reinterpret_cast<float*>(&Bsm[0][0]);
  const int slot = w & 3;
  if (kk == 1){
#pragma unroll
    for (int mr = 0; mr < 2; mr++)
#pragma unroll
      for (int nr = 0; nr < 4; nr++){
        int fid = mr * 4 + nr;
        int a = slot * 2048 + fid * 256 + r * 16 + ((hi + r) & 3) * 4;
        *reinterpret_cast<f32x4*>(&scr[a]) = acc[mr][nr];
      }
  }
  __syncthreads();
  if (kk == 0){
#pragma unroll
    for (int mr = 0; mr < 2; mr++)
#pragma unroll
      for (int nr = 0; nr < 4; nr++){
        int fid = mr * 4 + nr;
        int a = slot * 2048 + fid * 256 + r * 16 + ((hi + r) & 3) * 4;
        f32x4 t = *reinterpret_cast<const f32x4*>(&scr[a]);
        acc[mr][nr][0] += t[0]; acc[mr][nr][1] += t[1];
        acc[mr][nr][2] += t[2]; acc[mr][nr][3] += t[3];
      }

    if (z == 2){
#pragma unroll
      for (int mr = 0; mr < 2; mr++)
#pragma unroll
      for (int nr = 0; nr < 4; nr++){
          u16x4 o4 = { f2b(acc[mr][nr][0]), f2b(acc[mr][nr][1]),
                       f2b(acc[mr][nr][2]), f2b(acc[mr][nr][3]) };
          int col = tn + wc * 64 + nr * 16 + r;          // d index
          int row = tm + wr * 32 + mr * 16 + hi * 4;     // n index base
          *reinterpret_cast<u16x4*>(&vtb[(size_t)col * SN + row]) = o4;
        }
    } else {
      u16* outp = (z == 0) ? qb : kb;
      const float scl = (z == 0) ? 0.18033688011112043f : 1.0f;  // 0.125*log2(e)
#pragma unroll
      for (int mr = 0; mr < 2; mr++)
#pragma unroll
        for (int nr = 0; nr < 4; nr++)
#pragma unroll
          for (int j = 0; j < 4; j++){
            int row = tm + wr * 32 + mr * 16 + hi * 4 + j;
            int col = tn + wc * 64 + nr * 16 + r;
            outp[(size_t)row * SDIM + col] = f2b(acc[mr][nr][j] * scl);
          }
    }
  }
}

// ---------------- flash attention, no-max softmax, register P, KV-split x4 ----------------
// grid: (SN/256, SNH, 4) = 512 blocks, 512 threads (8 waves, 32 q-rows/wave).
// 8 waves share each staged KV tile. Cross-tile pipeline: iter t runs QK(t+1)
// and PV(t) back-to-back; exp/pack of tile t+1 overlaps PV(t). K tile i in
// klds[i&1] (staged 2 ahead), V tile i in vlds[i&1] (staged 1 ahead).
// NOTE: VGPR-capped at 2 blocks/CU — LB(512,5/6) spills catastrophically (r12/r15).
// NOTE: direct-from-global fragment loads are 64-way uncoalesced (r19) — keep LDS.
__global__ __launch_bounds__(512, 4) void attn(const u16* __restrict__ qb, const u16* __restrict__ kb,
                                               const u16* __restrict__ vtb,
                                               u16* __restrict__ po, float* __restrict__ pl){
  __shared__ __align__(16) u16 klds[2][64 * 64];
  __shared__ __align__(16) u16 vlds[2][64 * 64];
  const int tid = threadIdx.x, w = tid >> 6, lane = tid & 63;
  const int r = lane & 15, hi = lane >> 4;

  // bijective XCD swizzle over 512 blocks: XCD i gets sw in [i*64, (i+1)*64)
  // -> one z-quarter, 8 heads, 8 q-tiles (KV working set ~1 MB in its L2)
  int flat = blockIdx.x + 8 * blockIdx.y + 128 * blockIdx.z;   // 512 blocks
  int sw = (flat & 7) * 64 + (flat >> 3);
  const int q0 = (sw & 7) * 256, h = (sw >> 3) & 15, z = sw >> 7;

  const int srow_off = lane >> 3;
  const int schunk   = (lane & 7) ^ (lane >> 3);   // pre-swizzled source chunk

  // Q B-fragments, 2 subtiles (q = q0 + w*32 + sub*16 + r; 0.125*log2e folded)
  short8 aq[2][2];
#pragma unroll
  for (int sub = 0; sub < 2; sub++){
    int qrow = q0 + w * 32 + sub * 16 + r;
    aq[sub][0] = *reinterpret_cast<const short8*>(&qb[(size_t)qrow * SDIM + h * SDK + hi * 8]);
    aq[sub][1] = *reinterpret_cast<const short8*>(&qb[(size_t)qrow * SDIM + h * SDK + 32 + hi * 8]);
  }
  f32x4 oacc[2][4] = {};
  float lacc0 = 0.f, lacc1 = 0.f;   // per-lane partial row-sums (q = r per subtile)
  short8 paf0[2], paf1[2];          // current P A-fragments (pipeline register)

  // wave w stages rows [w*8, w*8+8) of the 64-row tile (one cp16 each)
  auto stageK = [&](int buf, int t){
    int rho = w * 8 + srow_off;   // LDS row
    // K-row permutation: kv stored at LDS row rho
    int kvp = 32 * (rho >> 5) + 8 * ((rho >> 2) & 3) + 4 * ((rho >> 4) & 1) + (rho & 3);
    async_cp16(kb + (size_t)(t + kvp) * SDIM + h * SDK + schunk * 8,
               &klds[buf][(w * 8) * 64]);
  };
  auto stageV = [&](int buf, int t){
    int rho = w * 8 + srow_off;
    async_cp16(vtb + (size_t)(h * SDK + rho) * SN + t + schunk * 8,
               &vlds[buf][(w * 8) * 64]);
  };

  // S^T = K Q^T (swapped): lane (r,hi), slot (ct,j) holds physical
  // kv = 32*(ct>>1) + 8*hi + 4*(ct&1) + j  (via the staging permutation)
  auto QK = [&](const u16* kbuf, f32x4* s0, f32x4* s1){
    __builtin_amdgcn_s_setprio(1);
#pragma unroll
    for (int ct = 0; ct < 4; ct++){
      int row = ct * 16 + r;
      int c0 = hi ^ (r & 7);
      short8 bk0 = *reinterpret_cast<const short8*>(&kbuf[row * 64 + c0 * 8]);
      short8 bk1 = *reinterpret_cast<const short8*>(&kbuf[row * 64 + (c0 ^ 4) * 8]);
      f32x4 zero = {};
      s0[ct] = __builtin_amdgcn_mfma_f32_16x16x32_bf16(bk0, aq[0][0], zero, 0, 0, 0);
      s1[ct] = __builtin_amdgcn_mfma_f32_16x16x32_bf16(bk0, aq[1][0], zero, 0, 0, 0);
      s0[ct] = __builtin_amdgcn_mfma_f32_16x16x32_bf16(bk1, aq[0][1], s0[ct], 0, 0, 0);
      s1[ct] = __builtin_amdgcn_mfma_f32_16x16x32_bf16(bk1, aq[1][1], s1[ct], 0, 0, 0);
    }
    __builtin_amdgcn_s_setprio(0);
  };

  // p = 2^s (bounded scores in log2 domain); pack into 16x16x32 A-fragments
  auto EXPPACK = [&](const f32x4* s0, const f32x4* s1){
    uint2 pc0[4], pc1[4];
#pragma unroll
    for (int ct = 0; ct < 4; ct++){
      float a0 = fast_exp2(s0[ct][0]), a1 = fast_exp2(s0[ct][1]);
      float a2 = fast_exp2(s0[ct][2]), a3 = fast_exp2(s0[ct][3]);
      lacc0 += (a0 + a1) + (a2 + a3);
      pc0[ct].x = packbf(a0, a1);
      pc0[ct].y = packbf(a2, a3);
      float b0 = fast_exp2(s1[ct][0]), b1 = fast_exp2(s1[ct][1]);
      float b2 = fast_exp2(s1[ct][2]), b3 = fast_exp2(s1[ct][3]);
      lacc1 += (b0 + b1) + (b2 + b3);
      pc1[ct].x = packbf(b0, b1);
      pc1[ct].y = packbf(b2, b3);
    }
#pragma unroll
    for (int c = 0; c < 2; c++){
      u32x4 u0 = { pc0[2*c].x, pc0[2*c].y, pc0[2*c+1].x, pc0[2*c+1].y };
      u32x4 u1 = { pc1[2*c].x, pc1[2*c].y, pc1[2*c+1].x, pc1[2*c+1].y };
      paf0[c] = __builtin_bit_cast(short8, u0);
      paf1[c] = __builtin_bit_cast(short8, u1);
    }
  };

  // O += P V : V B-frag is a b128 read (kv32 = 8hi..8hi+7 contiguous)
  auto PV = [&](const u16* vbuf){
    __builtin_amdgcn_s_setprio(1);
#pragma unroll
    for (int dt = 0; dt < 4; dt++){
      int row = dt * 16 + r;
      int swz = row & 7;
      short8 bvc[2];
#pragma unroll
      for (int c = 0; c < 2; c++)
        bvc[c] = *reinterpret_cast<const short8*>(&vbuf[row * 64 + ((4 * c + hi) ^ swz) * 8]);
#pragma unroll
      for (int c = 0; c < 2; c++){
        oacc[0][dt] = __builtin_amdgcn_mfma_f32_16x16x32_bf16(paf0[c], bvc[c], oacc[0][dt], 0, 0, 0);
        oacc[1][dt] = __builtin_amdgcn_mfma_f32_16x16x32_bf16(paf1[c], bvc[c], oacc[1][dt], 0, 0, 0);
      }
    }
    __builtin_amdgcn_s_setprio(0);
  };

  const int t0 = z * (SN / 4);
  const int NT = (SN / 4) / 64;   // 8 tiles

  // prologue: K0 -> klds[0], V0 -> vlds[0], K1 -> klds[1]
  stageK(0, t0); stageV(0, t0); stageK(1, t0 + 64);
  asm volatile("s_waitcnt vmcnt(0)" ::: "memory");
  __builtin_amdgcn_s_barrier();
  __builtin_amdgcn_sched_barrier(0);
  {
    f32x4 s0[4], s1[4];
    QK(&klds[0][0], s0, s1);
    EXPPACK(s0, s1);           // pa for tile 0
  }
  __builtin_amdgcn_s_barrier();  // all waves done reading klds[0] before iter0 overwrites it
  __builtin_amdgcn_sched_barrier(0);

  for (int it = 0; it < NT; ++it){
    const int cur = it & 1;
    const int t = t0 + it * 64;
    const bool hasN1 = (it + 1 < NT), hasN2 = (it + 2 < NT);
    if (hasN1) stageV(cur ^ 1, t + 64);      // V(t+1) -> vlds[(it+1)&1]
    if (hasN2) stageK(cur, t + 128);         // K(t+2) -> klds[(it+2)&1] = klds[cur]
    f32x4 s0[4], s1[4];
    if (hasN1) QK(&klds[cur ^ 1][0], s0, s1);  // scores for tile t+1
    PV(&vlds[cur][0]);                         // accumulate tile t with pa(t)
    if (hasN1) EXPPACK(s0, s1);                // pa for tile t+1 (overlaps PV exec)
    asm volatile("s_waitcnt vmcnt(0)" ::: "memory");
    __builtin_amdgcn_s_barrier();
    __builtin_amdgcn_sched_barrier(0);
  }

  // reduce l across the 4 hi-groups (q = r per subtile)
  lacc0 += __shfl_xor(lacc0, 16); lacc0 += __shfl_xor(lacc0, 32);
  lacc1 += __shfl_xor(lacc1, 16); lacc1 += __shfl_xor(lacc1, 32);

  const size_t zh = (size_t)z * SNH + h;
#pragma unroll
  for (int sub = 0; sub < 2; sub++)
#pragma unroll
    for (int dt = 0; dt < 4; dt++)
#pragma unroll
      for (int j = 0; j < 4; j++){
        int row = q0 + w * 32 + sub * 16 + hi * 4 + j;
        po[(zh * SN + row) * SDK + dt * 16 + r] = f2b(oacc[sub][dt][j]);
      }
  if (hi == 0){
    pl[zh * SN + q0 + w * 32 + r] = lacc0;
    pl[zh * SN + q0 + w * 32 + 16 + r] = lacc1;
  }
}

// ---------------- merge the four KV quarters (shared implicit max of 0) ----------------
// one thread per 8 output elems: b128 po reads, 2x dwordx4 out writes
__global__ void merge(const u16* __restrict__ po, const float* __restrict__ pl,
                      float* __restrict__ out){
  int gid = blockIdx.x * blockDim.x + threadIdx.x;  // 262144 threads
  int c8 = gid & 7;
  int rowid = gid >> 3;          // q*16 + h
  int h = rowid & 15, q = rowid >> 4;
  float L = 0.f;
  float o[8] = {};
#pragma unroll
  for (int z = 0; z < NZ; z++){
    size_t zh = (size_t)z * SNH + h;
    L += pl[zh * SN + q];
    u16x8 a = *reinterpret_cast<const u16x8*>(&po[(zh * SN + q) * SDK + c8 * 8]);
#pragma unroll
    for (int e = 0; e < 8; e++) o[e] += b2f(a[e]);
  }
  float rL = 1.0f / L;
  float4 o0 = { o[0] * rL, o[1] * rL, o[2] * rL, o[3] * rL };
  float4 o1 = { o[4] * rL, o[5] * rL, o[6] * rL, o[7] * rL };
  float* dst = &out[(size_t)q * SDIM + h * SDK + c8 * 8];
  *reinterpret_cast<float4*>(dst) = o0;
  *reinterpret_cast<float4*>(dst + 4) = o1;
}

extern "C" void kernel_launch(void* const* d_in, const int* in_sizes, int n_in,
                              void* d_out, int out_size, void* d_ws, size_t ws_size,
                              hipStream_t stream){
  const float* x  = (const float*)d_in[0];
  const float* Wq = (const float*)d_in[2];
  const float* Wk = (const float*)d_in[3];
  const float* Wv = (const float*)d_in[4];
  float* out = (float*)d_out;

  char* ws = (char*)d_ws;
  u16* xb  = (u16*)(ws);                   // 4 MB   x bf16
  u16* wb  = (u16*)(ws + (4  << 20));      // 6 MB   Wq|Wk|Wv bf16
  u16* qb  = (u16*)(ws + (10 << 20));      // 4 MB   q bf16 (pre-scaled by 0.125*log2e)
  u16* kb  = (u16*)(ws + (14 << 20));      // 4 MB   k bf16
  u16* vtb = (u16*)(ws + (18 << 20));      // 4 MB   v^T bf16 [1024][2048]
  u16* po  = (u16*)(ws + (22 << 20));      // 16 MB  [4][16][2048][64] bf16
  float* pl = (float*)(ws + (38 << 20));   // 512 KB [4][16][2048] f32

  conv_all<<<2048, 256, 0, stream>>>(x, Wq, Wk, Wv, xb, wb);

  dim3 pg(SN / 64, SDIM / 128, 3);         // (32, 8, 3) = 768 blocks, 64x128 tiles
  proj_gemm<<<pg, 512, 0, stream>>>(xb, wb, qb, kb, vtb);

  dim3 ag(SN / 256, SNH, NZ);              // (8, 16, 4) = 512 blocks, 512 threads
  attn<<<ag, 512, 0, stream>>>(qb, kb, vtb, po, pl);

  merge<<<(SN * SNH * 8) / 256, 256, 0, stream>>>(po, pl, out);
}